// Round 1
// baseline (102.632 us; speedup 1.0000x reference)
//
#include <hip/hip_runtime.h>

#define W_IMG 256
#define H_IMG 256
#define NPTS  1024

// One block per image row: 256 threads, 1 pixel/thread.
// Phase 1: all blocks redundantly compute per-gaussian params into LDS
//          (cheap: 1024 gaussians x ~30 ops per block).
// Phase 2: 1024-iteration accumulation loop, LDS broadcast reads.
__global__ __launch_bounds__(256) void gsplat_render(
    const float* __restrict__ xyz,       // (N,2)
    const float* __restrict__ chol,      // (N,3)
    const float* __restrict__ opac,      // (N,1)
    const float* __restrict__ feat,      // (N,3)
    float* __restrict__ out)             // (1,3,H,W) flat
{
    // AoS: per gaussian 8 floats = {cx, cy, CA, CB, CC, fr, fg, fb}
    __shared__ float4 sp4[NPTS * 2];
    float* sp = (float*)sp4;

    const float LOG2E = 1.4426950408889634f;
    for (int i = threadIdx.x; i < NPTS; i += 256) {
        float mx = tanhf(xyz[2 * i + 0]);
        float my = tanhf(xyz[2 * i + 1]);
        float cx = 0.5f * (float)W_IMG * (mx + 1.0f);
        float cy = 0.5f * (float)H_IMG * (my + 1.0f);
        float l1 = chol[3 * i + 0] + 0.5f;
        float l2 = chol[3 * i + 1];
        float l3 = chol[3 * i + 2] + 0.5f;
        float a = l1 * l1;
        float b = l1 * l2;
        float c = l2 * l2 + l3 * l3;
        float det = a * c - b * b;      // = l1^2 * l3^2 >= 0.0625, always > 0
        float inv = 1.0f / det;
        float o = opac[i];
        float* q = &sp[8 * i];
        q[0] = cx;
        q[1] = cy;
        // w = exp(-sigma) = exp2(CA*dx^2 + CB*dx*dy + CC*dy^2)
        // sigma = 0.5*(conic_a*dx^2 + conic_c*dy^2) + conic_b*dx*dy
        // conic_a = c/det, conic_b = -b/det, conic_c = a/det
        q[2] = -0.5f * c * inv * LOG2E;   // CA
        q[3] =         b * inv * LOG2E;   // CB  (= -conic_b*log2e)
        q[4] = -0.5f * a * inv * LOG2E;   // CC
        q[5] = feat[3 * i + 0] * o;
        q[6] = feat[3 * i + 1] * o;
        q[7] = feat[3 * i + 2] * o;
    }
    __syncthreads();

    const int x = threadIdx.x;
    const int y = blockIdx.x;
    const float px = (float)x + 0.5f;
    const float py = (float)y + 0.5f;

    float r = 0.0f, g = 0.0f, b = 0.0f;
    #pragma unroll 8
    for (int i = 0; i < NPTS; ++i) {
        float4 q0 = sp4[2 * i + 0];   // cx, cy, CA, CB
        float4 q1 = sp4[2 * i + 1];   // CC, fr, fg, fb
        float dx = px - q0.x;
        float dy = py - q0.y;
        float t  = fmaf(q0.z, dx, q0.w * dy);        // CA*dx + CB*dy
        float s  = fmaf(dx, t, (q1.x * dy) * dy);    // CA*dx^2 + CB*dx*dy + CC*dy^2
        float w  = exp2f(s);                          // = exp(-sigma)
        r = fmaf(w, q1.y, r);
        g = fmaf(w, q1.z, g);
        b = fmaf(w, q1.w, b);
    }

    const int p = y * W_IMG + x;
    out[0 * H_IMG * W_IMG + p] = fminf(fmaxf(r, 0.0f), 1.0f);
    out[1 * H_IMG * W_IMG + p] = fminf(fmaxf(g, 0.0f), 1.0f);
    out[2 * H_IMG * W_IMG + p] = fminf(fmaxf(b, 0.0f), 1.0f);
}

extern "C" void kernel_launch(void* const* d_in, const int* in_sizes, int n_in,
                              void* d_out, int out_size, void* d_ws, size_t ws_size,
                              hipStream_t stream) {
    const float* xyz  = (const float*)d_in[0];
    const float* chol = (const float*)d_in[1];
    const float* opac = (const float*)d_in[2];
    const float* feat = (const float*)d_in[3];
    float* out = (float*)d_out;
    (void)in_sizes; (void)n_in; (void)out_size; (void)d_ws; (void)ws_size;

    gsplat_render<<<H_IMG, 256, 0, stream>>>(xyz, chol, opac, feat, out);
}

// Round 2
// 62.422 us; speedup vs baseline: 1.6442x; 1.6442x over previous
//
#include <hip/hip_runtime.h>

#define W_IMG 256
#define H_IMG 256
#define NPTS  1024
#define SIG_CUT 15.0f   // skipped gaussians contribute < e^-15 each; 1024*e^-15 ~ 3e-4 << 0.02

// 16x16 pixel tiles, one block (256 threads) per tile.
// Phase 1: each thread computes params for 4 gaussians, bbox-tests them against
//          this tile, and compacts the survivors into LDS (slot via LDS atomic).
// Phase 2: every thread = 1 pixel; iterate only the compacted per-tile list.
__global__ __launch_bounds__(256) void gsplat_tiled(
    const float* __restrict__ xyz,       // (N,2)
    const float* __restrict__ chol,      // (N,3)
    const float* __restrict__ opac,      // (N,1)
    const float* __restrict__ feat,      // (N,3)
    float* __restrict__ out)             // (1,3,H,W) flat
{
    // compacted AoS: per survivor 8 floats = {cx, cy, CA, CB, CC, fr, fg, fb}
    __shared__ float4 sp4[NPTS * 2];
    __shared__ int scnt;

    const int tid = threadIdx.x;
    const int tx0 = (blockIdx.x & 15) << 4;
    const int ty0 = (blockIdx.x >> 4) << 4;

    if (tid == 0) scnt = 0;
    __syncthreads();

    const float LOG2E     = 1.4426950408889634f;
    const float TWO_LOG2E = 2.8853900817779268f;

    for (int i = tid; i < NPTS; i += 256) {
        // tanh(x) = 1 - 2/(exp(2x)+1), exp via v_exp_f32
        float e0 = exp2f(TWO_LOG2E * xyz[2 * i + 0]);
        float e1 = exp2f(TWO_LOG2E * xyz[2 * i + 1]);
        float mx = 1.0f - 2.0f * __builtin_amdgcn_rcpf(e0 + 1.0f);
        float my = 1.0f - 2.0f * __builtin_amdgcn_rcpf(e1 + 1.0f);
        float cx = 0.5f * (float)W_IMG * (mx + 1.0f);
        float cy = 0.5f * (float)H_IMG * (my + 1.0f);

        float l1 = chol[3 * i + 0] + 0.5f;
        float l2 = chol[3 * i + 1];
        float l3 = chol[3 * i + 2] + 0.5f;
        float a = l1 * l1;
        float b = l1 * l2;
        float c = fmaf(l2, l2, l3 * l3);

        // conservative bbox: sigma >= dx^2/(2a), dy^2/(2c)
        float rx = sqrtf(2.0f * SIG_CUT * a);
        float ry = sqrtf(2.0f * SIG_CUT * c);

        bool hit = (cx >= (float)tx0 - rx) && (cx <= (float)(tx0 + 16) + rx) &&
                   (cy >= (float)ty0 - ry) && (cy <= (float)(ty0 + 16) + ry);
        if (hit) {
            float det = fmaf(a, c, -b * b);          // = l1^2*l3^2 >= 0.0625
            float inv = __builtin_amdgcn_rcpf(det);
            float o = opac[i];
            int slot = atomicAdd(&scnt, 1);
            // w = exp(-sigma) = exp2(CA*dx^2 + CB*dx*dy + CC*dy^2)
            sp4[2 * slot + 0] = make_float4(cx, cy, -0.5f * c * inv * LOG2E, b * inv * LOG2E);
            sp4[2 * slot + 1] = make_float4(-0.5f * a * inv * LOG2E,
                                            feat[3 * i + 0] * o,
                                            feat[3 * i + 1] * o,
                                            feat[3 * i + 2] * o);
        }
    }
    __syncthreads();
    const int n = scnt;

    const int x = tx0 + (tid & 15);
    const int y = ty0 + (tid >> 4);
    const float px = (float)x + 0.5f;
    const float py = (float)y + 0.5f;

    float r = 0.0f, g = 0.0f, bl = 0.0f;
    #pragma unroll 4
    for (int j = 0; j < n; ++j) {
        float4 q0 = sp4[2 * j + 0];   // cx, cy, CA, CB
        float4 q1 = sp4[2 * j + 1];   // CC, fr, fg, fb
        float dx = px - q0.x;
        float dy = py - q0.y;
        float t  = fmaf(q0.z, dx, q0.w * dy);       // CA*dx + CB*dy
        float s  = fmaf(dx, t, (q1.x * dy) * dy);   // full quadratic
        float w  = exp2f(s);                        // = exp(-sigma)
        r  = fmaf(w, q1.y, r);
        g  = fmaf(w, q1.z, g);
        bl = fmaf(w, q1.w, bl);
    }

    const int p = y * W_IMG + x;
    out[0 * H_IMG * W_IMG + p] = fminf(fmaxf(r,  0.0f), 1.0f);
    out[1 * H_IMG * W_IMG + p] = fminf(fmaxf(g,  0.0f), 1.0f);
    out[2 * H_IMG * W_IMG + p] = fminf(fmaxf(bl, 0.0f), 1.0f);
}

extern "C" void kernel_launch(void* const* d_in, const int* in_sizes, int n_in,
                              void* d_out, int out_size, void* d_ws, size_t ws_size,
                              hipStream_t stream) {
    const float* xyz  = (const float*)d_in[0];
    const float* chol = (const float*)d_in[1];
    const float* opac = (const float*)d_in[2];
    const float* feat = (const float*)d_in[3];
    float* out = (float*)d_out;
    (void)in_sizes; (void)n_in; (void)out_size; (void)d_ws; (void)ws_size;

    gsplat_tiled<<<(W_IMG / 16) * (H_IMG / 16), 256, 0, stream>>>(xyz, chol, opac, feat, out);
}